// Round 4
// baseline (186.066 us; speedup 1.0000x reference)
//
#include <hip/hip_runtime.h>
#include <hip/hip_bf16.h>
#include <math.h>

#define BS 1024
#define D 128
#define NP 100000
#define PROWS 100096              // padded to multiple of 128 (96 zero rows)
#define CH 128                    // proxies per chunk/block
#define NCH (PROWS / CH)          // 782
#define NSLICE 16                 // rowsum slices (atomic contention / 16)
#define LOG2E 1.44269504088896340736f

typedef float f32x4 __attribute__((ext_vector_type(4)));
typedef float f32x16 __attribute__((ext_vector_type(16)));
typedef __bf16 bf16x8 __attribute__((ext_vector_type(8)));
typedef unsigned short u16x8 __attribute__((ext_vector_type(8)));

#if defined(__has_builtin)
#if __has_builtin(__builtin_amdgcn_exp2f)
#define FAST_EXP2(x) __builtin_amdgcn_exp2f(x)
#endif
#endif
#ifndef FAST_EXP2
#define FAST_EXP2(x) exp2f(x)
#endif

static __device__ __forceinline__ unsigned short f2bf(float x) {
    unsigned int u = __float_as_uint(x);
    return (unsigned short)((u + 0x7fffu + ((u >> 16) & 1u)) >> 16);  // RNE
}

// ---------- kernel 1: batch -> bf16 A (FRAGMENT-READY layout), d_pos ------
// A element (col,k) stored at byte
//   ((col>>5)*8 + (k>>4))*1024 + ((k>>3)&1)*512 + (col&31)*16 + (k&7)*2
// so main_kernel's B-frag load for (col_blk, s) is base + lane*16:
// one fully-coalesced 1KB load per wave instruction (was a 64-row gather).
// Layout validated in round 3 (absmax 0.0).
__global__ __launch_bounds__(256) void prep_kernel(
    const float* __restrict__ batch, const float* __restrict__ proxies,
    const int* __restrict__ labels, unsigned short* __restrict__ A,
    float* __restrict__ d_pos, float* __restrict__ rowsum,
    float* __restrict__ out)
{
    // zero the 16x1024 rowsum slices (128 blocks x 128 entries)
    if (threadIdx.x < 128) rowsum[blockIdx.x * 128 + threadIdx.x] = 0.f;
    if (blockIdx.x == 0 && threadIdx.x == 0) out[0] = 0.f;

    int wave = threadIdx.x >> 6, lane = threadIdx.x & 63;
    int sub = lane >> 5, c = lane & 31;
    int row = blockIdx.x * 8 + wave * 2 + sub;   // 0..1023  (= batch column)
    float4 v = *(const float4*)(batch + (size_t)row * D + c * 4);
    float ss = v.x*v.x + v.y*v.y + v.z*v.z + v.w*v.w;
    #pragma unroll
    for (int m = 1; m < 32; m <<= 1) ss += __shfl_xor(ss, m, 64);
    float sc = 3.0f / fmaxf(sqrtf(ss), 1e-12f);
    ushort4 pk;
    pk.x = f2bf(v.x*sc); pk.y = f2bf(v.y*sc);
    pk.z = f2bf(v.z*sc); pk.w = f2bf(v.w*sc);
    // k0 = 4c: s = c>>2, hi = (c>>1)&1, j0 = (c&1)*4
    {
        int col_blk = row >> 5, lr = row & 31;
        int s = c >> 2, h2 = (c >> 1) & 1, j0 = (c & 1) * 4;
        size_t off = (((size_t)(col_blk * 8 + s) * 2 + h2) << 9) + lr * 16 + j0 * 2;
        *(ushort4*)((char*)A + off) = pk;
    }
    // d_pos in fp32: 18 - 2*(b.p_label)
    int lab = labels[row];
    float4 p4 = *(const float4*)(proxies + (size_t)lab * D + c * 4);
    float ps = p4.x*p4.x + p4.y*p4.y + p4.z*p4.z + p4.w*p4.w;
    #pragma unroll
    for (int m = 1; m < 32; m <<= 1) ps += __shfl_xor(ps, m, 64);
    float psc = 3.0f / fmaxf(sqrtf(ps), 1e-12f);
    float dt = (v.x*sc)*(p4.x*psc) + (v.y*sc)*(p4.y*psc)
             + (v.z*sc)*(p4.z*psc) + (v.w*sc)*(p4.w*psc);
    #pragma unroll
    for (int m = 1; m < 32; m <<= 1) dt += __shfl_xor(dt, m, 64);
    if (c == 0) d_pos[row] = 18.0f - 2.0f * dt;
}

// ---------- kernel 2: fused proxy-norm + GEMM + exp row-sums --------------
// 256 threads (4 waves), block = 128 proxies staged into XOR-swizzled LDS
// (32 KB). mfma_f32_32x32x16_bf16; per-wave set Bf 32 + Af 32 + acc 16
// ~= 108 VGPR (round-2-proven, no spill). __launch_bounds__(256,4):
// 128-reg cap, 4 blocks/CU (LDS allows 5) -> 16 waves/CU AND grid
// capacity 1024 >= 782 blocks: whole grid co-resident, single dispatch
// round, staging barriers only stall 1/4 of a CU's waves at a time.
// Bf loads are COALESCED (fragment-ready A layout): one 1KB wave load
// per K-step instead of a 64-row gather -- the round-0/2 latency bomb.
// Each wave covers 256 batch cols (8 outers of 32) x all 128 proxies.
__global__ __launch_bounds__(256, 4) void main_kernel(
    const float* __restrict__ proxies,
    const unsigned short* __restrict__ Abat,   // fragment-ready layout
    float* __restrict__ rowsum)                // [NSLICE][BS]
{
    __shared__ unsigned short Plds[CH * D];    // 32 KB
    const int tid = threadIdx.x;
    const int lane = tid & 63;
    const int wave = tid >> 6;                 // 0..3
    const int l31 = lane & 31, hi = lane >> 5;
    const int chunk = blockIdx.x;

    // ---- staging: r = tid>>1 (0..127), q = tid&1 (64 floats each) --------
    {
        int r = tid >> 1, q = tid & 1;
        int pidx = chunk * CH + r;
        const float* src = proxies + (size_t)pidx * D + q * 64;
        float ss = 0.f;
        if (pidx < NP) {
            #pragma unroll
            for (int j = 0; j < 16; ++j) {
                float4 v = *(const float4*)(src + j * 4);
                ss += v.x*v.x + v.y*v.y + v.z*v.z + v.w*v.w;
            }
        }
        ss += __shfl_xor(ss, 1, 64);             // combine the 2 halves
        float sc = 3.0f / fmaxf(sqrtf(ss), 1e-12f);
        #pragma unroll
        for (int i2 = 0; i2 < 8; ++i2) {
            u16x8 w = (u16x8){0,0,0,0,0,0,0,0};
            if (pidx < NP) {
                float4 a = *(const float4*)(src + i2 * 8);      // L1/L2 hit
                float4 b = *(const float4*)(src + i2 * 8 + 4);
                w[0] = f2bf(a.x*sc); w[1] = f2bf(a.y*sc);
                w[2] = f2bf(a.z*sc); w[3] = f2bf(a.w*sc);
                w[4] = f2bf(b.x*sc); w[5] = f2bf(b.y*sc);
                w[6] = f2bf(b.z*sc); w[7] = f2bf(b.w*sc);
            }
            int cl = q * 8 + i2;                 // 16B chunk index in row
            *(u16x8*)((char*)Plds + r * 256 + ((cl ^ (r & 15)) << 4)) = w;
        }
    }
    __syncthreads();

    const float c1 = 2.0f * LOG2E, c0 = -18.0f * LOG2E;
    float* rs_base = rowsum + (size_t)(chunk & (NSLICE - 1)) * BS;
    const int rx = l31 & 15;                     // swizzle key for A reads

    #pragma unroll 1
    for (int outer = 0; outer < 8; ++outer) {
        // this wave's 32 batch columns for this pass
        const int col_blk = wave * 8 + outer;    // 0..31
        const int col0 = col_blk * 32;
        // B-cache: 32 cols x K=128 -> 8 x bf16x8 = 32 VGPRs.
        // COALESCED: per K-step s, the wave reads 1KB contiguous.
        const char* bp = (const char*)Abat + ((size_t)col_blk << 13) + lane * 16;
        bf16x8 Bf[8];
        #pragma unroll
        for (int s = 0; s < 8; ++s)
            Bf[s] = *(const bf16x8*)(bp + ((size_t)s << 10));

        float rs = 0.f;
        #pragma unroll
        for (int st = 0; st < 4; ++st) {
            // A-frags for proxy subtile st: row = st*32 + l31,
            // k = s*16 + hi*8 + j  (16B chunk cl = s*2+hi, XOR-swizzled)
            const char* arow = (const char*)Plds + (st * 32 + l31) * 256;
            bf16x8 Af[8];
            #pragma unroll
            for (int s = 0; s < 8; ++s)
                Af[s] = *(const bf16x8*)(arow + (((s * 2 + hi) ^ rx) << 4));
            f32x16 acc = {0.f,0.f,0.f,0.f,0.f,0.f,0.f,0.f,
                          0.f,0.f,0.f,0.f,0.f,0.f,0.f,0.f};
            #pragma unroll
            for (int s = 0; s < 8; ++s)
                acc = __builtin_amdgcn_mfma_f32_32x32x16_bf16(
                    Af[s], Bf[s], acc, 0, 0, 0);
            // epilogue: lane's batch col = col0 + l31; acc regs cover 16 of
            // the 32 proxy rows (other 16 live in the hi^1 half-wave).
            float e0 = 0.f, e1 = 0.f, e2 = 0.f, e3 = 0.f;
            #pragma unroll
            for (int r = 0; r < 4; ++r) {
                e0 += FAST_EXP2(fmaf(acc[4*r+0], c1, c0));
                e1 += FAST_EXP2(fmaf(acc[4*r+1], c1, c0));
                e2 += FAST_EXP2(fmaf(acc[4*r+2], c1, c0));
                e3 += FAST_EXP2(fmaf(acc[4*r+3], c1, c0));
            }
            rs += (e0 + e1) + (e2 + e3);
        }
        rs += __shfl_xor(rs, 32, 64);            // combine the two row-halves
        if (hi == 0)
            atomicAdd(rs_base + col0 + l31, rs);
    }
}

// ---------- kernel 3: final lse + mean (4 blocks, atomicAdd out) ----------
__global__ __launch_bounds__(256) void final_kernel(
    const float* __restrict__ rowsum, const float* __restrict__ d_pos,
    float* __restrict__ out)
{
    int row = blockIdx.x * 256 + threadIdx.x;
    float tot = 0.f;
    #pragma unroll
    for (int s = 0; s < NSLICE; ++s)
        tot += rowsum[(size_t)s * BS + row];
    float dp = d_pos[row];
    const float PADC = 96.0f * exp2f(-18.0f * LOG2E);  // zero-pad rows
    float neg = tot - expf(-dp) - PADC;                // drop own column
    float val = dp + logf(fmaxf(neg, 1e-37f));
    #pragma unroll
    for (int m = 1; m < 64; m <<= 1) val += __shfl_xor(val, m, 64);
    __shared__ float red[4];
    if ((threadIdx.x & 63) == 0) red[threadIdx.x >> 6] = val;
    __syncthreads();
    if (threadIdx.x == 0) {
        float v = (red[0] + red[1]) + (red[2] + red[3]);
        atomicAdd(out, v * (1.0f / 1024.0f));
    }
}

extern "C" void kernel_launch(void* const* d_in, const int* in_sizes, int n_in,
                              void* d_out, int out_size, void* d_ws, size_t ws_size,
                              hipStream_t stream) {
    const float* batch   = (const float*)d_in[0];
    const float* proxies = (const float*)d_in[1];
    const int*   labels  = (const int*)d_in[2];
    float* out = (float*)d_out;

    char* ws = (char*)d_ws;
    unsigned short* A  = (unsigned short*)ws;                    //   262,144 B
    float* d_pos       = (float*)(ws + 262144);                  //     4,096 B
    float* rowsum      = (float*)(ws + 266240);                  //    65,536 B

    prep_kernel<<<128, 256, 0, stream>>>(batch, proxies, labels, A, d_pos, rowsum, out);
    main_kernel<<<NCH, 256, 0, stream>>>(proxies, A, rowsum);
    final_kernel<<<4, 256, 0, stream>>>(rowsum, d_pos, out);
}

// Round 5
// 132.045 us; speedup vs baseline: 1.4091x; 1.4091x over previous
//
#include <hip/hip_runtime.h>
#include <hip/hip_bf16.h>
#include <math.h>

#define BS 1024
#define D 128
#define NP 100000
#define PROWS 100096              // padded to multiple of 128 (96 zero rows)
#define CH 128                    // proxies per chunk/block
#define NCH (PROWS / CH)          // 782
#define NSLICE 16                 // rowsum slices (atomic contention / 16)
#define LOG2E 1.44269504088896340736f

typedef float f32x4 __attribute__((ext_vector_type(4)));
typedef float f32x16 __attribute__((ext_vector_type(16)));
typedef __bf16 bf16x8 __attribute__((ext_vector_type(8)));
typedef unsigned short u16x8 __attribute__((ext_vector_type(8)));

#if defined(__has_builtin)
#if __has_builtin(__builtin_amdgcn_exp2f)
#define FAST_EXP2(x) __builtin_amdgcn_exp2f(x)
#endif
#endif
#ifndef FAST_EXP2
#define FAST_EXP2(x) exp2f(x)
#endif

static __device__ __forceinline__ unsigned short f2bf(float x) {
    unsigned int u = __float_as_uint(x);
    return (unsigned short)((u + 0x7fffu + ((u >> 16) & 1u)) >> 16);  // RNE
}

// ---------- kernel 1: batch -> bf16 A (FRAGMENT-READY layout), d_pos ------
// A element (col,k) stored at byte
//   ((col>>5)*8 + (k>>4))*1024 + ((k>>3)&1)*512 + (col&31)*16 + (k&7)*2
// so main_kernel's B-frag load for (col_blk, s) is base + lane*16:
// one fully-coalesced 1KB load per wave instruction (was a 32-line gather).
// Layout validated in rounds 3 and 4 (absmax 0.0).
__global__ __launch_bounds__(256) void prep_kernel(
    const float* __restrict__ batch, const float* __restrict__ proxies,
    const int* __restrict__ labels, unsigned short* __restrict__ A,
    float* __restrict__ d_pos, float* __restrict__ rowsum,
    float* __restrict__ out)
{
    // zero the 16x1024 rowsum slices (128 blocks x 128 entries)
    if (threadIdx.x < 128) rowsum[blockIdx.x * 128 + threadIdx.x] = 0.f;
    if (blockIdx.x == 0 && threadIdx.x == 0) out[0] = 0.f;

    int wave = threadIdx.x >> 6, lane = threadIdx.x & 63;
    int sub = lane >> 5, c = lane & 31;
    int row = blockIdx.x * 8 + wave * 2 + sub;   // 0..1023  (= batch column)
    float4 v = *(const float4*)(batch + (size_t)row * D + c * 4);
    float ss = v.x*v.x + v.y*v.y + v.z*v.z + v.w*v.w;
    #pragma unroll
    for (int m = 1; m < 32; m <<= 1) ss += __shfl_xor(ss, m, 64);
    float sc = 3.0f / fmaxf(sqrtf(ss), 1e-12f);
    ushort4 pk;
    pk.x = f2bf(v.x*sc); pk.y = f2bf(v.y*sc);
    pk.z = f2bf(v.z*sc); pk.w = f2bf(v.w*sc);
    // k0 = 4c: s = c>>2, hi = (c>>1)&1, j0 = (c&1)*4
    {
        int col_blk = row >> 5, lr = row & 31;
        int s = c >> 2, h2 = (c >> 1) & 1, j0 = (c & 1) * 4;
        size_t off = (((size_t)(col_blk * 8 + s) * 2 + h2) << 9) + lr * 16 + j0 * 2;
        *(ushort4*)((char*)A + off) = pk;
    }
    // d_pos in fp32: 18 - 2*(b.p_label)
    int lab = labels[row];
    float4 p4 = *(const float4*)(proxies + (size_t)lab * D + c * 4);
    float ps = p4.x*p4.x + p4.y*p4.y + p4.z*p4.z + p4.w*p4.w;
    #pragma unroll
    for (int m = 1; m < 32; m <<= 1) ps += __shfl_xor(ps, m, 64);
    float psc = 3.0f / fmaxf(sqrtf(ps), 1e-12f);
    float dt = (v.x*sc)*(p4.x*psc) + (v.y*sc)*(p4.y*psc)
             + (v.z*sc)*(p4.z*psc) + (v.w*sc)*(p4.w*psc);
    #pragma unroll
    for (int m = 1; m < 32; m <<= 1) dt += __shfl_xor(dt, m, 64);
    if (c == 0) d_pos[row] = 18.0f - 2.0f * dt;
}

// ---------- kernel 2: fused proxy-norm + GEMM + exp row-sums --------------
// EXACT round-2 structure (71us, 108 VGPR, zero spill, absmax 0.0) with ONE
// change: Bf loads are coalesced via the fragment-ready A layout (one 1KB
// wave-load per K-step, base + lane*16) instead of a 32-line row-gather.
// Single-variable test of the gather-bottleneck theory.
// 512 threads (8 waves), CH=128 proxies in XOR-swizzled LDS (32 KB).
// __launch_bounds__(512, 2): the ONLY bounds that has ever produced the
// no-spill ~108-reg compile. arg=4 empirically caps at 64 regs -> spills.
__global__ __launch_bounds__(512, 2) void main_kernel(
    const float* __restrict__ proxies,
    const unsigned short* __restrict__ Abat,   // fragment-ready layout
    float* __restrict__ rowsum)                // [NSLICE][BS]
{
    __shared__ unsigned short Plds[CH * D];    // 32 KB
    const int tid = threadIdx.x;
    const int lane = tid & 63;
    const int wave = tid >> 6;
    const int l31 = lane & 31, hi = lane >> 5;
    const int chunk = blockIdx.x;

    // ---- staging: r = tid>>2 (0..127), q = tid&3 (32 floats each) --------
    {
        int r = tid >> 2, q = tid & 3;
        int pidx = chunk * CH + r;
        const float* src = proxies + (size_t)pidx * D + q * 32;
        float ss = 0.f;
        if (pidx < NP) {
            #pragma unroll
            for (int j = 0; j < 8; ++j) {
                float4 v = *(const float4*)(src + j * 4);
                ss += v.x*v.x + v.y*v.y + v.z*v.z + v.w*v.w;
            }
        }
        ss += __shfl_xor(ss, 1, 64);             // combine 4 quarters
        ss += __shfl_xor(ss, 2, 64);
        float sc = 3.0f / fmaxf(sqrtf(ss), 1e-12f);
        #pragma unroll
        for (int i2 = 0; i2 < 4; ++i2) {
            u16x8 w = (u16x8){0,0,0,0,0,0,0,0};
            if (pidx < NP) {
                float4 a = *(const float4*)(src + i2 * 8);      // L2 hit
                float4 b = *(const float4*)(src + i2 * 8 + 4);
                w[0] = f2bf(a.x*sc); w[1] = f2bf(a.y*sc);
                w[2] = f2bf(a.z*sc); w[3] = f2bf(a.w*sc);
                w[4] = f2bf(b.x*sc); w[5] = f2bf(b.y*sc);
                w[6] = f2bf(b.z*sc); w[7] = f2bf(b.w*sc);
            }
            int cl = q * 4 + i2;                 // 16B chunk index in row
            *(u16x8*)((char*)Plds + r * 256 + ((cl ^ (r & 15)) << 4)) = w;
        }
    }
    __syncthreads();

    const float c1 = 2.0f * LOG2E, c0 = -18.0f * LOG2E;
    float* rs_base = rowsum + (size_t)(chunk & (NSLICE - 1)) * BS;
    const int rx = l31 & 15;                     // swizzle key for A reads

    #pragma unroll 1
    for (int outer = 0; outer < 4; ++outer) {
        // this wave's 32 batch columns for this pass
        const int col_blk = outer * 8 + wave;    // 0..31
        const int col0 = col_blk * 32;
        // B-cache: 32 cols x K=128 -> 8 x bf16x8 = 32 VGPRs.
        // COALESCED: per K-step s, the wave reads 1KB contiguous.
        const char* bp = (const char*)Abat + ((size_t)col_blk << 13) + lane * 16;
        bf16x8 Bf[8];
        #pragma unroll
        for (int s = 0; s < 8; ++s)
            Bf[s] = *(const bf16x8*)(bp + ((size_t)s << 10));

        float rs = 0.f;
        #pragma unroll
        for (int st = 0; st < 4; ++st) {
            // A-frags for proxy subtile st: row = st*32 + l31,
            // k = s*16 + hi*8 + j  (16B chunk cl = s*2+hi, XOR-swizzled)
            const char* arow = (const char*)Plds + (st * 32 + l31) * 256;
            bf16x8 Af[8];
            #pragma unroll
            for (int s = 0; s < 8; ++s)
                Af[s] = *(const bf16x8*)(arow + (((s * 2 + hi) ^ rx) << 4));
            f32x16 acc = {0.f,0.f,0.f,0.f,0.f,0.f,0.f,0.f,
                          0.f,0.f,0.f,0.f,0.f,0.f,0.f,0.f};
            #pragma unroll
            for (int s = 0; s < 8; ++s)
                acc = __builtin_amdgcn_mfma_f32_32x32x16_bf16(
                    Af[s], Bf[s], acc, 0, 0, 0);
            // epilogue: lane's batch col = col0 + l31; acc regs cover 16 of
            // the 32 proxy rows (other 16 live in the hi^1 half-wave).
            float e0 = 0.f, e1 = 0.f, e2 = 0.f, e3 = 0.f;
            #pragma unroll
            for (int r = 0; r < 4; ++r) {
                e0 += FAST_EXP2(fmaf(acc[4*r+0], c1, c0));
                e1 += FAST_EXP2(fmaf(acc[4*r+1], c1, c0));
                e2 += FAST_EXP2(fmaf(acc[4*r+2], c1, c0));
                e3 += FAST_EXP2(fmaf(acc[4*r+3], c1, c0));
            }
            rs += (e0 + e1) + (e2 + e3);
        }
        rs += __shfl_xor(rs, 32, 64);            // combine the two row-halves
        if (hi == 0)
            atomicAdd(rs_base + col0 + l31, rs);
    }
}

// ---------- kernel 3: final lse + mean (4 blocks, atomicAdd out) ----------
__global__ __launch_bounds__(256) void final_kernel(
    const float* __restrict__ rowsum, const float* __restrict__ d_pos,
    float* __restrict__ out)
{
    int row = blockIdx.x * 256 + threadIdx.x;
    float tot = 0.f;
    #pragma unroll
    for (int s = 0; s < NSLICE; ++s)
        tot += rowsum[(size_t)s * BS + row];
    float dp = d_pos[row];
    const float PADC = 96.0f * exp2f(-18.0f * LOG2E);  // zero-pad rows
    float neg = tot - expf(-dp) - PADC;                // drop own column
    float val = dp + logf(fmaxf(neg, 1e-37f));
    #pragma unroll
    for (int m = 1; m < 64; m <<= 1) val += __shfl_xor(val, m, 64);
    __shared__ float red[4];
    if ((threadIdx.x & 63) == 0) red[threadIdx.x >> 6] = val;
    __syncthreads();
    if (threadIdx.x == 0) {
        float v = (red[0] + red[1]) + (red[2] + red[3]);
        atomicAdd(out, v * (1.0f / 1024.0f));
    }
}

extern "C" void kernel_launch(void* const* d_in, const int* in_sizes, int n_in,
                              void* d_out, int out_size, void* d_ws, size_t ws_size,
                              hipStream_t stream) {
    const float* batch   = (const float*)d_in[0];
    const float* proxies = (const float*)d_in[1];
    const int*   labels  = (const int*)d_in[2];
    float* out = (float*)d_out;

    char* ws = (char*)d_ws;
    unsigned short* A  = (unsigned short*)ws;                    //   262,144 B
    float* d_pos       = (float*)(ws + 262144);                  //     4,096 B
    float* rowsum      = (float*)(ws + 266240);                  //    65,536 B

    prep_kernel<<<128, 256, 0, stream>>>(batch, proxies, labels, A, d_pos, rowsum, out);
    main_kernel<<<NCH, 512, 0, stream>>>(proxies, A, rowsum);
    final_kernel<<<4, 256, 0, stream>>>(rowsum, d_pos, out);
}

// Round 6
// 128.756 us; speedup vs baseline: 1.4451x; 1.0255x over previous
//
#include <hip/hip_runtime.h>
#include <hip/hip_bf16.h>
#include <math.h>

#define BS 1024
#define D 128
#define NP 100000
#define PROWS 100096              // padded to multiple of 128 (96 zero rows)
#define CH 128                    // proxies per chunk/block
#define NCH (PROWS / CH)          // 782
#define NSLICE 16                 // rowsum slices (atomic contention / 16)
#define LOG2E 1.44269504088896340736f

typedef float f32x4 __attribute__((ext_vector_type(4)));
typedef float f32x16 __attribute__((ext_vector_type(16)));
typedef __bf16 bf16x8 __attribute__((ext_vector_type(8)));
typedef unsigned short u16x8 __attribute__((ext_vector_type(8)));

#if defined(__has_builtin)
#if __has_builtin(__builtin_amdgcn_exp2f)
#define FAST_EXP2(x) __builtin_amdgcn_exp2f(x)
#endif
#endif
#ifndef FAST_EXP2
#define FAST_EXP2(x) exp2f(x)
#endif

static __device__ __forceinline__ unsigned short f2bf(float x) {
    unsigned int u = __float_as_uint(x);
    return (unsigned short)((u + 0x7fffu + ((u >> 16) & 1u)) >> 16);  // RNE
}

// ---------- kernel 1: batch -> bf16 A (FRAGMENT-READY layout), d_pos ------
// A element (col,k) stored at byte
//   ((col>>5)*8 + (k>>4))*1024 + ((k>>3)&1)*512 + (col&31)*16 + (k&7)*2
// so main_kernel's B-frag load for (col_blk, s) is base + lane*16:
// one fully-coalesced 1KB load per wave instruction (was a 32-line gather).
// Layout validated rounds 3-5 (absmax 0.0). Worth -15% on main (round 5).
__global__ __launch_bounds__(256) void prep_kernel(
    const float* __restrict__ batch, const float* __restrict__ proxies,
    const int* __restrict__ labels, unsigned short* __restrict__ A,
    float* __restrict__ d_pos, float* __restrict__ rowsum,
    float* __restrict__ out)
{
    // zero the 16x1024 rowsum slices (128 blocks x 128 entries)
    if (threadIdx.x < 128) rowsum[blockIdx.x * 128 + threadIdx.x] = 0.f;
    if (blockIdx.x == 0 && threadIdx.x == 0) out[0] = 0.f;

    int wave = threadIdx.x >> 6, lane = threadIdx.x & 63;
    int sub = lane >> 5, c = lane & 31;
    int row = blockIdx.x * 8 + wave * 2 + sub;   // 0..1023  (= batch column)
    float4 v = *(const float4*)(batch + (size_t)row * D + c * 4);
    float ss = v.x*v.x + v.y*v.y + v.z*v.z + v.w*v.w;
    #pragma unroll
    for (int m = 1; m < 32; m <<= 1) ss += __shfl_xor(ss, m, 64);
    float sc = 3.0f / fmaxf(sqrtf(ss), 1e-12f);
    ushort4 pk;
    pk.x = f2bf(v.x*sc); pk.y = f2bf(v.y*sc);
    pk.z = f2bf(v.z*sc); pk.w = f2bf(v.w*sc);
    // k0 = 4c: s = c>>2, hi = (c>>1)&1, j0 = (c&1)*4
    {
        int col_blk = row >> 5, lr = row & 31;
        int s = c >> 2, h2 = (c >> 1) & 1, j0 = (c & 1) * 4;
        size_t off = (((size_t)(col_blk * 8 + s) * 2 + h2) << 9) + lr * 16 + j0 * 2;
        *(ushort4*)((char*)A + off) = pk;
    }
    // d_pos in fp32: 18 - 2*(b.p_label)
    int lab = labels[row];
    float4 p4 = *(const float4*)(proxies + (size_t)lab * D + c * 4);
    float ps = p4.x*p4.x + p4.y*p4.y + p4.z*p4.z + p4.w*p4.w;
    #pragma unroll
    for (int m = 1; m < 32; m <<= 1) ps += __shfl_xor(ps, m, 64);
    float psc = 3.0f / fmaxf(sqrtf(ps), 1e-12f);
    float dt = (v.x*sc)*(p4.x*psc) + (v.y*sc)*(p4.y*psc)
             + (v.z*sc)*(p4.z*psc) + (v.w*sc)*(p4.w*psc);
    #pragma unroll
    for (int m = 1; m < 32; m <<= 1) dt += __shfl_xor(dt, m, 64);
    if (c == 0) d_pos[row] = 18.0f - 2.0f * dt;
}

// ---------- kernel 2: fused proxy-norm + GEMM + exp row-sums --------------
// 256 threads (4 waves), CH=128 proxies in XOR-swizzled LDS (32 KB).
// Round-5 inner structure (coalesced Bf via fragment-ready A, 60.6us) with
// FINER DISPATCH GRANULARITY: 4-wave blocks at ~108 VGPR -> 16 waves/CU ->
// 4 blocks/CU -> grid capacity 1024 >= 782: single co-resident round (round
// 5's 512-thread blocks ran 1.53 rounds; ~47% of CUs idle in round 2), and
// the staging barrier stalls only 1/4 of a CU's waves at a time.
// __launch_bounds__ law (4 data points, rounds 1/2/4/5): reg cap = 256/arg2
// regardless of block size. (256,2) -> 128-reg cap -> the proven no-spill
// ~108-reg compile. NEVER arg=4 (64-reg cap -> 50MB spill traffic).
__global__ __launch_bounds__(256, 2) void main_kernel(
    const float* __restrict__ proxies,
    const unsigned short* __restrict__ Abat,   // fragment-ready layout
    float* __restrict__ rowsum)                // [NSLICE][BS]
{
    __shared__ unsigned short Plds[CH * D];    // 32 KB
    const int tid = threadIdx.x;
    const int lane = tid & 63;
    const int wave = tid >> 6;                 // 0..3
    const int l31 = lane & 31, hi = lane >> 5;
    const int chunk = blockIdx.x;

    // ---- staging: r = tid>>1 (0..127), q = tid&1 (64 floats each) --------
    {
        int r = tid >> 1, q = tid & 1;
        int pidx = chunk * CH + r;
        const float* src = proxies + (size_t)pidx * D + q * 64;
        float ss = 0.f;
        if (pidx < NP) {
            #pragma unroll
            for (int j = 0; j < 16; ++j) {
                float4 v = *(const float4*)(src + j * 4);
                ss += v.x*v.x + v.y*v.y + v.z*v.z + v.w*v.w;
            }
        }
        ss += __shfl_xor(ss, 1, 64);             // combine the 2 halves
        float sc = 3.0f / fmaxf(sqrtf(ss), 1e-12f);
        #pragma unroll
        for (int i2 = 0; i2 < 8; ++i2) {
            u16x8 w = (u16x8){0,0,0,0,0,0,0,0};
            if (pidx < NP) {
                float4 a = *(const float4*)(src + i2 * 8);      // L1/L2 hit
                float4 b = *(const float4*)(src + i2 * 8 + 4);
                w[0] = f2bf(a.x*sc); w[1] = f2bf(a.y*sc);
                w[2] = f2bf(a.z*sc); w[3] = f2bf(a.w*sc);
                w[4] = f2bf(b.x*sc); w[5] = f2bf(b.y*sc);
                w[6] = f2bf(b.z*sc); w[7] = f2bf(b.w*sc);
            }
            int cl = q * 8 + i2;                 // 16B chunk index in row
            *(u16x8*)((char*)Plds + r * 256 + ((cl ^ (r & 15)) << 4)) = w;
        }
    }
    __syncthreads();

    const float c1 = 2.0f * LOG2E, c0 = -18.0f * LOG2E;
    float* rs_base = rowsum + (size_t)(chunk & (NSLICE - 1)) * BS;
    const int rx = l31 & 15;                     // swizzle key for A reads

    #pragma unroll 1
    for (int outer = 0; outer < 8; ++outer) {
        // this wave's 32 batch columns for this pass
        const int col_blk = wave * 8 + outer;    // 0..31
        const int col0 = col_blk * 32;
        // B-cache: 32 cols x K=128 -> 8 x bf16x8 = 32 VGPRs.
        // COALESCED: per K-step s, the wave reads 1KB contiguous.
        const char* bp = (const char*)Abat + ((size_t)col_blk << 13) + lane * 16;
        bf16x8 Bf[8];
        #pragma unroll
        for (int s = 0; s < 8; ++s)
            Bf[s] = *(const bf16x8*)(bp + ((size_t)s << 10));

        float rs = 0.f;
        #pragma unroll
        for (int st = 0; st < 4; ++st) {
            // A-frags for proxy subtile st: row = st*32 + l31,
            // k = s*16 + hi*8 + j  (16B chunk cl = s*2+hi, XOR-swizzled)
            const char* arow = (const char*)Plds + (st * 32 + l31) * 256;
            bf16x8 Af[8];
            #pragma unroll
            for (int s = 0; s < 8; ++s)
                Af[s] = *(const bf16x8*)(arow + (((s * 2 + hi) ^ rx) << 4));
            f32x16 acc = {0.f,0.f,0.f,0.f,0.f,0.f,0.f,0.f,
                          0.f,0.f,0.f,0.f,0.f,0.f,0.f,0.f};
            #pragma unroll
            for (int s = 0; s < 8; ++s)
                acc = __builtin_amdgcn_mfma_f32_32x32x16_bf16(
                    Af[s], Bf[s], acc, 0, 0, 0);
            // epilogue: lane's batch col = col0 + l31; acc regs cover 16 of
            // the 32 proxy rows (other 16 live in the hi^1 half-wave).
            float e0 = 0.f, e1 = 0.f, e2 = 0.f, e3 = 0.f;
            #pragma unroll
            for (int r = 0; r < 4; ++r) {
                e0 += FAST_EXP2(fmaf(acc[4*r+0], c1, c0));
                e1 += FAST_EXP2(fmaf(acc[4*r+1], c1, c0));
                e2 += FAST_EXP2(fmaf(acc[4*r+2], c1, c0));
                e3 += FAST_EXP2(fmaf(acc[4*r+3], c1, c0));
            }
            rs += (e0 + e1) + (e2 + e3);
        }
        rs += __shfl_xor(rs, 32, 64);            // combine the two row-halves
        if (hi == 0)
            atomicAdd(rs_base + col0 + l31, rs);
    }
}

// ---------- kernel 3: final lse + mean (4 blocks, atomicAdd out) ----------
__global__ __launch_bounds__(256) void final_kernel(
    const float* __restrict__ rowsum, const float* __restrict__ d_pos,
    float* __restrict__ out)
{
    int row = blockIdx.x * 256 + threadIdx.x;
    float tot = 0.f;
    #pragma unroll
    for (int s = 0; s < NSLICE; ++s)
        tot += rowsum[(size_t)s * BS + row];
    float dp = d_pos[row];
    const float PADC = 96.0f * exp2f(-18.0f * LOG2E);  // zero-pad rows
    float neg = tot - expf(-dp) - PADC;                // drop own column
    float val = dp + logf(fmaxf(neg, 1e-37f));
    #pragma unroll
    for (int m = 1; m < 64; m <<= 1) val += __shfl_xor(val, m, 64);
    __shared__ float red[4];
    if ((threadIdx.x & 63) == 0) red[threadIdx.x >> 6] = val;
    __syncthreads();
    if (threadIdx.x == 0) {
        float v = (red[0] + red[1]) + (red[2] + red[3]);
        atomicAdd(out, v * (1.0f / 1024.0f));
    }
}

extern "C" void kernel_launch(void* const* d_in, const int* in_sizes, int n_in,
                              void* d_out, int out_size, void* d_ws, size_t ws_size,
                              hipStream_t stream) {
    const float* batch   = (const float*)d_in[0];
    const float* proxies = (const float*)d_in[1];
    const int*   labels  = (const int*)d_in[2];
    float* out = (float*)d_out;

    char* ws = (char*)d_ws;
    unsigned short* A  = (unsigned short*)ws;                    //   262,144 B
    float* d_pos       = (float*)(ws + 262144);                  //     4,096 B
    float* rowsum      = (float*)(ws + 266240);                  //    65,536 B

    prep_kernel<<<128, 256, 0, stream>>>(batch, proxies, labels, A, d_pos, rowsum, out);
    main_kernel<<<NCH, 256, 0, stream>>>(proxies, A, rowsum);
    final_kernel<<<4, 256, 0, stream>>>(rowsum, d_pos, out);
}